// Round 1
// baseline (3387.778 us; speedup 1.0000x reference)
//
#include <hip/hip_runtime.h>
#include <math.h>

#define N_TOK 16384
#define DIM   2048
#define NEXP  64
#define TOPK  8

#define BM 128
#define BN 128
#define BK 16

// ---------------------------------------------------------------------------
// Kernel 1: h = gelu(x @ W1 + b1) computed tile-wise in registers (never
// materialized); epilogue accumulates partial logits Lp[r,e] += h_tile @ W2
// via 16-lane shuffle reduction + atomicAdd. Pure fp32 for top-k exactness.
// ---------------------------------------------------------------------------
__global__ __launch_bounds__(256) void gemm_router_stage1(
    const float* __restrict__ x, const float* __restrict__ W1,
    const float* __restrict__ b1, const float* __restrict__ W2,
    float* __restrict__ Lp)
{
    __shared__ float As[BK][BM + 4];   // x tile, transposed; +4 pad keeps f4 align
    __shared__ float Bs[BK][BN];       // W1 tile

    const int t  = threadIdx.x;
    const int tx = t & 15;             // 16 col-threads
    const int ty = t >> 4;             // 16 row-threads
    const int m0 = blockIdx.y * BM;
    const int n0 = blockIdx.x * BN;

    float acc[8][8];
    #pragma unroll
    for (int i = 0; i < 8; i++)
        #pragma unroll
        for (int j = 0; j < 8; j++) acc[i][j] = 0.f;

    for (int k0 = 0; k0 < DIM; k0 += BK) {
        // stage x tile [BM x BK] -> As[k][m] (transposed)
        #pragma unroll
        for (int it = 0; it < 2; it++) {
            int s   = t + it * 256;
            int row = s >> 2;          // 0..127
            int kq  = (s & 3) * 4;     // 0,4,8,12
            const float4 v = *(const float4*)(x + (size_t)(m0 + row) * DIM + k0 + kq);
            As[kq + 0][row] = v.x;
            As[kq + 1][row] = v.y;
            As[kq + 2][row] = v.z;
            As[kq + 3][row] = v.w;
        }
        // stage W1 tile [BK x BN] -> Bs[k][n]
        #pragma unroll
        for (int it = 0; it < 2; it++) {
            int s   = t + it * 256;
            int row = s >> 5;          // 0..15
            int c4  = (s & 31) * 4;    // 0..124
            *(float4*)(&Bs[row][c4]) =
                *(const float4*)(W1 + (size_t)(k0 + row) * DIM + n0 + c4);
        }
        __syncthreads();
        #pragma unroll
        for (int kk = 0; kk < BK; kk++) {
            float a[8], b[8];
            *(float4*)(a)     = *(const float4*)(&As[kk][ty * 8]);
            *(float4*)(a + 4) = *(const float4*)(&As[kk][ty * 8 + 4]);
            *(float4*)(b)     = *(const float4*)(&Bs[kk][tx * 8]);
            *(float4*)(b + 4) = *(const float4*)(&Bs[kk][tx * 8 + 4]);
            #pragma unroll
            for (int i = 0; i < 8; i++)
                #pragma unroll
                for (int j = 0; j < 8; j++)
                    acc[i][j] = fmaf(a[i], b[j], acc[i][j]);
        }
        __syncthreads();
    }

    // epilogue: bias + exact (erf) GELU, in place
    float bv[8];
    #pragma unroll
    for (int j = 0; j < 8; j++) bv[j] = b1[n0 + tx * 8 + j];
    #pragma unroll
    for (int i = 0; i < 8; i++)
        #pragma unroll
        for (int j = 0; j < 8; j++) {
            float h = acc[i][j] + bv[j];
            acc[i][j] = 0.5f * h * (1.0f + erff(h * 0.70710678118654752440f));
        }

    // partial logits: Lp[m0+ty*8+i, e] += sum over this block's 128 n-cols.
    // Threads sharing ty (16 tx values = lanes differing in bits 0..3 of the
    // wave) each own 8 n's; shuffle-reduce then one atomic per (row, e).
    const int nbase = n0 + tx * 8;
    for (int e = 0; e < NEXP; e++) {
        float w2j[8];
        #pragma unroll
        for (int j = 0; j < 8; j++) w2j[j] = W2[(size_t)(nbase + j) * NEXP + e];
        #pragma unroll
        for (int i = 0; i < 8; i++) {
            float v = 0.f;
            #pragma unroll
            for (int j = 0; j < 8; j++) v = fmaf(acc[i][j], w2j[j], v);
            v += __shfl_xor(v, 1);
            v += __shfl_xor(v, 2);
            v += __shfl_xor(v, 4);
            v += __shfl_xor(v, 8);
            if (tx == 0)
                atomicAdd(&Lp[(size_t)(m0 + ty * 8 + i) * NEXP + e], v);
        }
    }
}

// ---------------------------------------------------------------------------
// Kernel 2: per-token routing. One wave per token, lane = expert.
// ---------------------------------------------------------------------------
__global__ __launch_bounds__(256) void router_topk(
    const float* __restrict__ Lp, const float* __restrict__ b2,
    float* __restrict__ out_rw, float* __restrict__ out_idx,
    float* __restrict__ gP, float* __restrict__ gI)
{
    __shared__ float sP[NEXP];
    __shared__ float sI[NEXP];
    const int t = threadIdx.x;
    if (t < NEXP) { sP[t] = 0.f; sI[t] = 0.f; }
    __syncthreads();

    const int lane = t & 63;
    const int wv   = t >> 6;
    const int tok  = blockIdx.x * 4 + wv;

    float logit = Lp[(size_t)tok * NEXP + lane] + b2[lane];

    // full softmax over 64 experts (for load-balance loss)
    float mx = logit;
    #pragma unroll
    for (int off = 32; off >= 1; off >>= 1)
        mx = fmaxf(mx, __shfl_xor(mx, off));
    float p  = expf(logit - mx);
    float ps = p;
    #pragma unroll
    for (int off = 32; off >= 1; off >>= 1)
        ps += __shfl_xor(ps, off);
    p = p / ps;

    // iterative top-8 argmax (min-index tiebreak = lax.top_k stability)
    float cur = logit;
    float tv[TOPK];
    int   tix[TOPK];
    for (int k = 0; k < TOPK; k++) {
        float v = cur;
        int idx = lane;
        #pragma unroll
        for (int off = 32; off >= 1; off >>= 1) {
            float ov = __shfl_xor(v, off);
            int   oi = __shfl_xor(idx, off);
            if (ov > v || (ov == v && oi < idx)) { v = ov; idx = oi; }
        }
        tv[k] = v; tix[k] = idx;
        if (lane == idx) cur = -INFINITY;
    }

    // softmax over the 8 selected (tv[0] is the max)
    float ev[TOPK];
    float s = 0.f;
    #pragma unroll
    for (int k = 0; k < TOPK; k++) { ev[k] = expf(tv[k] - tv[0]); s += ev[k]; }
    float w   = 0.f;
    float sel = 0.f;
    #pragma unroll
    for (int k = 0; k < TOPK; k++)
        if (tix[k] == lane) { w = ev[k] / s; sel = 1.f; }

    out_rw[(size_t)tok * NEXP + lane] = w;
    if (lane < TOPK) out_idx[(size_t)tok * TOPK + lane] = (float)tix[lane];

    atomicAdd(&sP[lane], p);
    atomicAdd(&sI[lane], sel);
    __syncthreads();
    if (t < NEXP) {
        atomicAdd(&gP[t], sP[t]);
        atomicAdd(&gI[t], sI[t]);
    }
}

// ---------------------------------------------------------------------------
// Kernel 3: loss = E * sum_e (freq_e * avg_prob_e)
// ---------------------------------------------------------------------------
__global__ void loss_kernel(const float* __restrict__ gP,
                            const float* __restrict__ gI,
                            float* __restrict__ out_loss)
{
    const int lane = threadIdx.x;
    const float inv = 1.0f / (float)N_TOK;
    float v = (gI[lane] * inv) * (gP[lane] * inv);
    #pragma unroll
    for (int off = 32; off >= 1; off >>= 1)
        v += __shfl_xor(v, off);
    if (lane == 0) out_loss[0] = (float)NEXP * v;
}

extern "C" void kernel_launch(void* const* d_in, const int* in_sizes, int n_in,
                              void* d_out, int out_size, void* d_ws, size_t ws_size,
                              hipStream_t stream) {
    const float* x  = (const float*)d_in[0];
    const float* W1 = (const float*)d_in[1];
    const float* b1 = (const float*)d_in[2];
    const float* W2 = (const float*)d_in[3];
    const float* b2 = (const float*)d_in[4];

    float* out_rw   = (float*)d_out;                        // N*E
    float* out_idx  = out_rw + (size_t)N_TOK * NEXP;        // N*TOPK (as float)
    float* out_loss = out_idx + (size_t)N_TOK * TOPK;       // 1

    float* Lp = (float*)d_ws;                               // N*E logits accumulator
    float* gP = Lp + (size_t)N_TOK * NEXP;                  // 64 prob sums
    float* gI = gP + NEXP;                                  // 64 freq sums

    // d_ws is re-poisoned to 0xAA before every launch -> zero what we accumulate into
    hipMemsetAsync(d_ws, 0, ((size_t)N_TOK * NEXP + 2 * NEXP) * sizeof(float), stream);

    dim3 g1(DIM / BN, N_TOK / BM);                          // 16 x 128 blocks
    gemm_router_stage1<<<g1, 256, 0, stream>>>(x, W1, b1, W2, Lp);
    router_topk<<<N_TOK / 4, 256, 0, stream>>>(Lp, b2, out_rw, out_idx, gP, gI);
    loss_kernel<<<1, 64, 0, stream>>>(gP, gI, out_loss);
}

// Round 3
// 775.984 us; speedup vs baseline: 4.3658x; 4.3658x over previous
//
#include <hip/hip_runtime.h>
#include <math.h>
#include <stdint.h>

#define N_TOK 16384
#define DIM   2048
#define NEXP  64
#define TOPK  8

#define BM 128
#define BN 128
#define BKE 32          // k-elements staged per iteration

typedef _Float16 half8 __attribute__((ext_vector_type(8)));
typedef float    f32x4 __attribute__((ext_vector_type(4)));

#define GLOBAL_AS __attribute__((address_space(1)))
#define LDS_AS    __attribute__((address_space(3)))

#define LO_SCALE     4096.0f
#define INV_LO_SCALE (1.0f / 4096.0f)

// pack fp32 v -> u32: low16 = fp16(v), high16 = fp16((v - fp16(v)) * 4096)
__device__ inline uint32_t pack_split(float v) {
    _Float16 hi = (_Float16)v;
    float r = (v - (float)hi) * LO_SCALE;
    _Float16 lo = (_Float16)r;
    return (uint32_t)__builtin_bit_cast(uint16_t, hi) |
           ((uint32_t)__builtin_bit_cast(uint16_t, lo) << 16);
}

union U4H8 { uint32_t u[4]; half8 h; };

// read 8 packed u32 (one MFMA k-fragment) from a swizzled LDS tile row and
// split into hi / lo_scaled half8 fragments.
// LDS tile: [rows][8 chunks of 16B]; chunk c holds global chunk (c ^ (row&7)).
__device__ inline void load_frag(const uint32_t* base, int row, int quad,
                                 half8& hi, half8& lo) {
    const int sw = row & 7;
    const uint4 q0 = *(const uint4*)(base + row * 32 + (((quad * 2)     ^ sw) << 2));
    const uint4 q1 = *(const uint4*)(base + row * 32 + (((quad * 2 + 1) ^ sw) << 2));
    uint32_t u[8] = {q0.x, q0.y, q0.z, q0.w, q1.x, q1.y, q1.z, q1.w};
    U4H8 H, L;
    #pragma unroll
    for (int j = 0; j < 4; j++) {
        H.u[j] = (u[2 * j] & 0xffffu) | (u[2 * j + 1] << 16);
        L.u[j] = (u[2 * j] >> 16)     | (u[2 * j + 1] & 0xffff0000u);
    }
    hi = H.h; lo = L.h;
}

// ---------------------------------------------------------------------------
// conversion kernels
// ---------------------------------------------------------------------------
__global__ __launch_bounds__(256) void convert_x(float* __restrict__ x) {
    size_t i = ((size_t)blockIdx.x * 256 + threadIdx.x) * 4;
    float4 v = *(const float4*)(x + i);
    uint4 p;
    p.x = pack_split(v.x); p.y = pack_split(v.y);
    p.z = pack_split(v.z); p.w = pack_split(v.w);
    *(uint4*)(x + i) = p;
}

__global__ __launch_bounds__(256) void convert_w1t(const float* __restrict__ W1,
                                                   uint32_t* __restrict__ W1Tp) {
    __shared__ float s[32][33];
    const int k0 = blockIdx.y * 32, n0 = blockIdx.x * 32;
    const int tr = threadIdx.x & 31, tc = threadIdx.x >> 5;   // 32 x 8
    #pragma unroll
    for (int r = 0; r < 4; r++) {
        int row = tc + r * 8;
        s[row][tr] = W1[(size_t)(k0 + row) * DIM + n0 + tr];
    }
    __syncthreads();
    #pragma unroll
    for (int r = 0; r < 4; r++) {
        int row = tc + r * 8;                                 // n-local
        W1Tp[(size_t)(n0 + row) * DIM + k0 + tr] = pack_split(s[tr][row]);
    }
}

__global__ __launch_bounds__(256) void convert_w2t(const float* __restrict__ W2,
                                                   uint32_t* __restrict__ W2Tp) {
    int i = blockIdx.x * 256 + threadIdx.x;   // over 64*2048
    int e = i >> 11, n = i & 2047;
    W2Tp[i] = pack_split(W2[(size_t)n * NEXP + e]);
}

// ---------------------------------------------------------------------------
// fused GEMM1 (x@W1 + b1, GELU) + GEMM2 (h@W2) -> partial logits (atomic)
// ---------------------------------------------------------------------------
__global__ __launch_bounds__(256, 2) void gemm_fused(
    const uint32_t* __restrict__ xp, const uint32_t* __restrict__ W1Tp,
    const float* __restrict__ b1, const uint32_t* __restrict__ W2Tp,
    float* __restrict__ Lp)
{
    __shared__ uint32_t smem[16384];          // 64 KB (union main/epilogue)
    uint32_t* Ap = smem;                      // [128][32] packed u32
    uint32_t* Bp = smem + 4096;               // [128][32]

    const int t    = threadIdx.x;
    const int wid  = t >> 6;
    const int lane = t & 63;
    const int quad = lane >> 4;
    const int l16  = lane & 15;

    // block swizzle: groups of 8 m-blocks share one n-block (W1T slice L2 reuse)
    const int lin = blockIdx.x;               // 2048 blocks
    const int grp = lin >> 7;
    const int rem = lin & 127;
    const int m0 = (grp * 8 + (rem & 7)) * BM;
    const int n0 = (rem >> 3) * BN;

    // per-round staging addresses (swizzle applied on the GLOBAL side)
    const uint32_t* gA[4];
    const uint32_t* gB[4];
    #pragma unroll
    for (int r = 0; r < 4; r++) {
        int s = r * 256 + t;
        int row = s >> 3;
        int c   = s & 7;
        int co  = (c ^ (row & 7)) << 2;       // swizzled element offset in row
        gA[r] = xp   + (size_t)(m0 + row) * DIM + co;
        gB[r] = W1Tp + (size_t)(n0 + row) * DIM + co;
    }

    f32x4 am[4][4], ac[4][4];
    #pragma unroll
    for (int i = 0; i < 4; i++)
        #pragma unroll
        for (int j = 0; j < 4; j++) { am[i][j] = (f32x4)0.0f; ac[i][j] = (f32x4)0.0f; }

    const int wm = (wid & 1) * 64;
    const int wn = (wid >> 1) * 64;

    for (int k0 = 0; k0 < DIM; k0 += BKE) {
        #pragma unroll
        for (int r = 0; r < 4; r++) {
            const int wslot = (r * 256 + wid * 64) << 2;  // wave-uniform LDS word
            __builtin_amdgcn_global_load_lds((const GLOBAL_AS uint32_t*)gA[r],
                                             (LDS_AS uint32_t*)(Ap + wslot), 16, 0, 0);
            __builtin_amdgcn_global_load_lds((const GLOBAL_AS uint32_t*)gB[r],
                                             (LDS_AS uint32_t*)(Bp + wslot), 16, 0, 0);
            gA[r] += BKE; gB[r] += BKE;
        }
        __syncthreads();   // drains vmcnt -> staged data visible

        half8 ah[4], al[4], bh[4], bl[4];
        #pragma unroll
        for (int mt = 0; mt < 4; mt++)
            load_frag(Ap, wm + mt * 16 + l16, quad, ah[mt], al[mt]);
        #pragma unroll
        for (int nt = 0; nt < 4; nt++)
            load_frag(Bp, wn + nt * 16 + l16, quad, bh[nt], bl[nt]);

        #pragma unroll
        for (int mt = 0; mt < 4; mt++)
            #pragma unroll
            for (int nt = 0; nt < 4; nt++) {
                am[mt][nt] = __builtin_amdgcn_mfma_f32_16x16x32_f16(ah[mt], bh[nt], am[mt][nt], 0, 0, 0);
                ac[mt][nt] = __builtin_amdgcn_mfma_f32_16x16x32_f16(ah[mt], bl[nt], ac[mt][nt], 0, 0, 0);
                ac[mt][nt] = __builtin_amdgcn_mfma_f32_16x16x32_f16(al[mt], bh[nt], ac[mt][nt], 0, 0, 0);
            }
        __syncthreads();   // before next stage overwrites LDS
    }

    // ---- epilogue: bias + exact GELU, pack h into swizzled LDS [128][128] ----
    uint32_t* Hs = smem;
    #pragma unroll
    for (int mt = 0; mt < 4; mt++)
        #pragma unroll
        for (int nt = 0; nt < 4; nt++) {
            const int coln = wn + nt * 16 + l16;
            const float b1v = b1[n0 + coln];
            #pragma unroll
            for (int r = 0; r < 4; r++) {
                float h = am[mt][nt][r] + ac[mt][nt][r] * INV_LO_SCALE + b1v;
                h = 0.5f * h * (1.0f + erff(h * 0.70710678118654752440f));
                const int rowm = wm + mt * 16 + quad * 4 + r;
                const int word = rowm * 128 + ((((coln >> 2) ^ (rowm & 7)) << 2) | (coln & 3));
                Hs[word] = pack_split(h);
            }
        }
    __syncthreads();

    // ---- GEMM2: logits[128 x 64] = h[128 x 128] @ W2T'  (K=32 per MFMA,
    //      4 k-steps cover the 128 h-columns) ----
    f32x4 a2m[2][4], a2c[2][4];
    #pragma unroll
    for (int i = 0; i < 2; i++)
        #pragma unroll
        for (int j = 0; j < 4; j++) { a2m[i][j] = (f32x4)0.0f; a2c[i][j] = (f32x4)0.0f; }

    #pragma unroll
    for (int ks = 0; ks < 4; ks++) {
        half8 a2h[2], a2l[2];
        #pragma unroll
        for (int mt2 = 0; mt2 < 2; mt2++) {
            const int row = wid * 32 + mt2 * 16 + l16;
            const int sw  = row & 7;
            const int cb  = ks * 8 + quad * 2;           // k = ks*32 + quad*8 + j
            const uint4 q0 = *(const uint4*)(Hs + row * 128 + ((cb ^ sw) << 2));
            const uint4 q1 = *(const uint4*)(Hs + row * 128 + (((cb + 1) ^ sw) << 2));
            uint32_t u[8] = {q0.x, q0.y, q0.z, q0.w, q1.x, q1.y, q1.z, q1.w};
            U4H8 H, L;
            #pragma unroll
            for (int j = 0; j < 4; j++) {
                H.u[j] = (u[2 * j] & 0xffffu) | (u[2 * j + 1] << 16);
                L.u[j] = (u[2 * j] >> 16)     | (u[2 * j + 1] & 0xffff0000u);
            }
            a2h[mt2] = H.h; a2l[mt2] = L.h;
        }
        #pragma unroll
        for (int et = 0; et < 4; et++) {
            const int e = et * 16 + l16;
            const uint32_t* wp = W2Tp + (size_t)e * DIM + n0 + ks * 32 + quad * 8;
            const uint4 q0 = *(const uint4*)wp;
            const uint4 q1 = *(const uint4*)(wp + 4);
            uint32_t u[8] = {q0.x, q0.y, q0.z, q0.w, q1.x, q1.y, q1.z, q1.w};
            U4H8 H, L;
            #pragma unroll
            for (int j = 0; j < 4; j++) {
                H.u[j] = (u[2 * j] & 0xffffu) | (u[2 * j + 1] << 16);
                L.u[j] = (u[2 * j] >> 16)     | (u[2 * j + 1] & 0xffff0000u);
            }
            #pragma unroll
            for (int mt2 = 0; mt2 < 2; mt2++) {
                a2m[mt2][et] = __builtin_amdgcn_mfma_f32_16x16x32_f16(a2h[mt2], H.h, a2m[mt2][et], 0, 0, 0);
                a2c[mt2][et] = __builtin_amdgcn_mfma_f32_16x16x32_f16(a2h[mt2], L.h, a2c[mt2][et], 0, 0, 0);
                a2c[mt2][et] = __builtin_amdgcn_mfma_f32_16x16x32_f16(a2l[mt2], H.h, a2c[mt2][et], 0, 0, 0);
            }
        }
    }

    #pragma unroll
    for (int mt2 = 0; mt2 < 2; mt2++)
        #pragma unroll
        for (int et = 0; et < 4; et++)
            #pragma unroll
            for (int r = 0; r < 4; r++) {
                const float lg = a2m[mt2][et][r] + a2c[mt2][et][r] * INV_LO_SCALE;
                const int rowm = m0 + wid * 32 + mt2 * 16 + quad * 4 + r;
                const int e = et * 16 + l16;
                atomicAdd(&Lp[(size_t)rowm * NEXP + e], lg);
            }
}

// ---------------------------------------------------------------------------
// fallback fp32 vector GEMM (used only if ws_size is too small) — round-1 code
// ---------------------------------------------------------------------------
__global__ __launch_bounds__(256) void gemm_router_stage1(
    const float* __restrict__ x, const float* __restrict__ W1,
    const float* __restrict__ b1, const float* __restrict__ W2,
    float* __restrict__ Lp)
{
    __shared__ float As[16][BM + 4];
    __shared__ float Bs[16][BN];
    const int t  = threadIdx.x;
    const int tx = t & 15, ty = t >> 4;
    const int m0 = blockIdx.y * BM, n0 = blockIdx.x * BN;
    float acc[8][8];
    #pragma unroll
    for (int i = 0; i < 8; i++)
        #pragma unroll
        for (int j = 0; j < 8; j++) acc[i][j] = 0.f;
    for (int k0 = 0; k0 < DIM; k0 += 16) {
        #pragma unroll
        for (int it = 0; it < 2; it++) {
            int s = t + it * 256, row = s >> 2, kq = (s & 3) * 4;
            const float4 v = *(const float4*)(x + (size_t)(m0 + row) * DIM + k0 + kq);
            As[kq + 0][row] = v.x; As[kq + 1][row] = v.y;
            As[kq + 2][row] = v.z; As[kq + 3][row] = v.w;
        }
        #pragma unroll
        for (int it = 0; it < 2; it++) {
            int s = t + it * 256, row = s >> 5, c4 = (s & 31) * 4;
            *(float4*)(&Bs[row][c4]) = *(const float4*)(W1 + (size_t)(k0 + row) * DIM + n0 + c4);
        }
        __syncthreads();
        #pragma unroll
        for (int kk = 0; kk < 16; kk++) {
            float a[8], b[8];
            *(float4*)(a)     = *(const float4*)(&As[kk][ty * 8]);
            *(float4*)(a + 4) = *(const float4*)(&As[kk][ty * 8 + 4]);
            *(float4*)(b)     = *(const float4*)(&Bs[kk][tx * 8]);
            *(float4*)(b + 4) = *(const float4*)(&Bs[kk][tx * 8 + 4]);
            #pragma unroll
            for (int i = 0; i < 8; i++)
                #pragma unroll
                for (int j = 0; j < 8; j++) acc[i][j] = fmaf(a[i], b[j], acc[i][j]);
        }
        __syncthreads();
    }
    float bv[8];
    #pragma unroll
    for (int j = 0; j < 8; j++) bv[j] = b1[n0 + tx * 8 + j];
    #pragma unroll
    for (int i = 0; i < 8; i++)
        #pragma unroll
        for (int j = 0; j < 8; j++) {
            float h = acc[i][j] + bv[j];
            acc[i][j] = 0.5f * h * (1.0f + erff(h * 0.70710678118654752440f));
        }
    const int nbase = n0 + tx * 8;
    for (int e = 0; e < NEXP; e++) {
        float w2j[8];
        #pragma unroll
        for (int j = 0; j < 8; j++) w2j[j] = W2[(size_t)(nbase + j) * NEXP + e];
        #pragma unroll
        for (int i = 0; i < 8; i++) {
            float v = 0.f;
            #pragma unroll
            for (int j = 0; j < 8; j++) v = fmaf(acc[i][j], w2j[j], v);
            v += __shfl_xor(v, 1); v += __shfl_xor(v, 2);
            v += __shfl_xor(v, 4); v += __shfl_xor(v, 8);
            if (tx == 0) atomicAdd(&Lp[(size_t)(m0 + ty * 8 + i) * NEXP + e], v);
        }
    }
}

// ---------------------------------------------------------------------------
// routing + loss (unchanged)
// ---------------------------------------------------------------------------
__global__ __launch_bounds__(256) void router_topk(
    const float* __restrict__ Lp, const float* __restrict__ b2,
    float* __restrict__ out_rw, float* __restrict__ out_idx,
    float* __restrict__ gP, float* __restrict__ gI)
{
    __shared__ float sP[NEXP];
    __shared__ float sI[NEXP];
    const int t = threadIdx.x;
    if (t < NEXP) { sP[t] = 0.f; sI[t] = 0.f; }
    __syncthreads();

    const int lane = t & 63;
    const int tok  = blockIdx.x * 4 + (t >> 6);

    float logit = Lp[(size_t)tok * NEXP + lane] + b2[lane];

    float mx = logit;
    #pragma unroll
    for (int off = 32; off >= 1; off >>= 1) mx = fmaxf(mx, __shfl_xor(mx, off));
    float p = expf(logit - mx);
    float ps = p;
    #pragma unroll
    for (int off = 32; off >= 1; off >>= 1) ps += __shfl_xor(ps, off);
    p = p / ps;

    float cur = logit;
    float tv[TOPK]; int tix[TOPK];
    for (int k = 0; k < TOPK; k++) {
        float v = cur; int idx = lane;
        #pragma unroll
        for (int off = 32; off >= 1; off >>= 1) {
            float ov = __shfl_xor(v, off);
            int   oi = __shfl_xor(idx, off);
            if (ov > v || (ov == v && oi < idx)) { v = ov; idx = oi; }
        }
        tv[k] = v; tix[k] = idx;
        if (lane == idx) cur = -INFINITY;
    }

    float ev[TOPK], s = 0.f;
    #pragma unroll
    for (int k = 0; k < TOPK; k++) { ev[k] = expf(tv[k] - tv[0]); s += ev[k]; }
    float w = 0.f, sel = 0.f;
    #pragma unroll
    for (int k = 0; k < TOPK; k++)
        if (tix[k] == lane) { w = ev[k] / s; sel = 1.f; }

    out_rw[(size_t)tok * NEXP + lane] = w;
    if (lane < TOPK) out_idx[(size_t)tok * TOPK + lane] = (float)tix[lane];

    atomicAdd(&sP[lane], p);
    atomicAdd(&sI[lane], sel);
    __syncthreads();
    if (t < NEXP) { atomicAdd(&gP[t], sP[t]); atomicAdd(&gI[t], sI[t]); }
}

__global__ void loss_kernel(const float* __restrict__ gP,
                            const float* __restrict__ gI,
                            float* __restrict__ out_loss)
{
    const int lane = threadIdx.x;
    const float inv = 1.0f / (float)N_TOK;
    float v = (gI[lane] * inv) * (gP[lane] * inv);
    #pragma unroll
    for (int off = 32; off >= 1; off >>= 1) v += __shfl_xor(v, off);
    if (lane == 0) out_loss[0] = (float)NEXP * v;
}

extern "C" void kernel_launch(void* const* d_in, const int* in_sizes, int n_in,
                              void* d_out, int out_size, void* d_ws, size_t ws_size,
                              hipStream_t stream) {
    const float* x  = (const float*)d_in[0];
    const float* W1 = (const float*)d_in[1];
    const float* b1 = (const float*)d_in[2];
    const float* W2 = (const float*)d_in[3];
    const float* b2 = (const float*)d_in[4];

    float* out_rw   = (float*)d_out;
    float* out_idx  = out_rw + (size_t)N_TOK * NEXP;
    float* out_loss = out_idx + (size_t)N_TOK * TOPK;

    const size_t OFF_W1T = 0;
    const size_t OFF_W2T = (size_t)16 << 20;
    const size_t OFF_LP  = (size_t)17 << 20;
    const size_t OFF_G   = OFF_LP + (size_t)N_TOK * NEXP * 4;
    const size_t needed  = OFF_G + 2 * NEXP * 4;

    if (ws_size >= needed) {
        uint32_t* W1Tp = (uint32_t*)((char*)d_ws + OFF_W1T);
        uint32_t* W2Tp = (uint32_t*)((char*)d_ws + OFF_W2T);
        float* Lp = (float*)((char*)d_ws + OFF_LP);
        float* gP = (float*)((char*)d_ws + OFF_G);
        float* gI = gP + NEXP;

        hipMemsetAsync((char*)d_ws + OFF_LP, 0,
                       (size_t)N_TOK * NEXP * 4 + 2 * NEXP * 4, stream);
        convert_x  <<<(N_TOK * DIM) / (256 * 4), 256, 0, stream>>>((float*)d_in[0]);
        convert_w1t<<<dim3(DIM / 32, DIM / 32), 256, 0, stream>>>(W1, W1Tp);
        convert_w2t<<<(NEXP * DIM) / 256, 256, 0, stream>>>(W2, W2Tp);
        gemm_fused<<<(N_TOK / BM) * (DIM / BN), 256, 0, stream>>>(
            (const uint32_t*)d_in[0], W1Tp, b1, W2Tp, Lp);
        router_topk<<<N_TOK / 4, 256, 0, stream>>>(Lp, b2, out_rw, out_idx, gP, gI);
        loss_kernel<<<1, 64, 0, stream>>>(gP, gI, out_loss);
    } else {
        // fallback: round-1 fp32 vector path (Lp at ws base)
        float* Lp = (float*)d_ws;
        float* gP = Lp + (size_t)N_TOK * NEXP;
        float* gI = gP + NEXP;
        hipMemsetAsync(d_ws, 0, ((size_t)N_TOK * NEXP + 2 * NEXP) * sizeof(float), stream);
        dim3 g1(DIM / BN, N_TOK / BM);
        gemm_router_stage1<<<g1, 256, 0, stream>>>(x, W1, b1, W2, Lp);
        router_topk<<<N_TOK / 4, 256, 0, stream>>>(Lp, b2, out_rw, out_idx, gP, gI);
        loss_kernel<<<1, 64, 0, stream>>>(gP, gI, out_loss);
    }
}

// Round 5
// 765.118 us; speedup vs baseline: 4.4278x; 1.0142x over previous
//
#include <hip/hip_runtime.h>
#include <math.h>
#include <stdint.h>

#define N_TOK 16384
#define DIM   2048
#define NEXP  64
#define TOPK  8

#define BM 128
#define BN 128
#define BKE 32          // k-elements staged per iteration

typedef _Float16 half8 __attribute__((ext_vector_type(8)));
typedef _Float16 half4 __attribute__((ext_vector_type(4)));
typedef float    f32x4 __attribute__((ext_vector_type(4)));

#define GLOBAL_AS __attribute__((address_space(1)))
#define LDS_AS    __attribute__((address_space(3)))

#define LO_SCALE     4096.0f
#define INV_LO_SCALE (1.0f / 4096.0f)

// pack fp32 v -> u32: low16 = fp16(v), high16 = fp16((v - fp16(v)) * 4096)
__device__ inline uint32_t pack_split(float v) {
    _Float16 hi = (_Float16)v;
    float r = (v - (float)hi) * LO_SCALE;
    _Float16 lo = (_Float16)r;
    return (uint32_t)__builtin_bit_cast(uint16_t, hi) |
           ((uint32_t)__builtin_bit_cast(uint16_t, lo) << 16);
}

__device__ inline _Float16 split_hi(float v) { return (_Float16)v; }
__device__ inline _Float16 split_lo(float v) {
    _Float16 hi = (_Float16)v;
    return (_Float16)((v - (float)hi) * LO_SCALE);
}

union U4H8 { uint32_t u[4]; half8 h; };

// round-3 packed-u32 fragment loader (used by fallback + epilogue W2 reads)
__device__ inline void load_frag(const uint32_t* base, int row, int quad,
                                 half8& hi, half8& lo) {
    const int sw = row & 7;
    const uint4 q0 = *(const uint4*)(base + row * 32 + (((quad * 2)     ^ sw) << 2));
    const uint4 q1 = *(const uint4*)(base + row * 32 + (((quad * 2 + 1) ^ sw) << 2));
    uint32_t u[8] = {q0.x, q0.y, q0.z, q0.w, q1.x, q1.y, q1.z, q1.w};
    U4H8 H, L;
    #pragma unroll
    for (int j = 0; j < 4; j++) {
        H.u[j] = (u[2 * j] & 0xffffu) | (u[2 * j + 1] << 16);
        L.u[j] = (u[2 * j] >> 16)     | (u[2 * j + 1] & 0xffff0000u);
    }
    hi = H.h; lo = L.h;
}

// clean split-array fragment loader: zero unpack VALU, one b128 per fragment.
// LDS row = 64 halves = [32 hi | 32 lo] = 8 slots of 16B; logical chunk c
// (0-3 hi k-chunks, 4-7 lo k-chunks) lives at slot c ^ (row&7).
__device__ inline void load_frag2(const _Float16* base, int row, int quad,
                                  half8& hi, half8& lo) {
    const int sw = row & 7;
    hi = *(const half8*)(base + row * 64 + ((quad       ^ sw) << 3));
    lo = *(const half8*)(base + row * 64 + (((quad + 4) ^ sw) << 3));
}

// ---------------------------------------------------------------------------
// conversion kernels — split path (separate hi/lo half arrays in ws)
// ---------------------------------------------------------------------------
__global__ __launch_bounds__(256) void convert_x_split(
    const float* __restrict__ x, _Float16* __restrict__ xhi,
    _Float16* __restrict__ xlo)
{
    size_t i = ((size_t)blockIdx.x * 256 + threadIdx.x) * 4;
    float4 v = *(const float4*)(x + i);
    half4 h, l;
    h.x = split_hi(v.x); l.x = split_lo(v.x);
    h.y = split_hi(v.y); l.y = split_lo(v.y);
    h.z = split_hi(v.z); l.z = split_lo(v.z);
    h.w = split_hi(v.w); l.w = split_lo(v.w);
    *(half4*)(xhi + i) = h;
    *(half4*)(xlo + i) = l;
}

__global__ __launch_bounds__(256) void convert_w1t_split(
    const float* __restrict__ W1, _Float16* __restrict__ w1hi,
    _Float16* __restrict__ w1lo)
{
    __shared__ float s[32][33];
    const int k0 = blockIdx.y * 32, n0 = blockIdx.x * 32;
    const int tr = threadIdx.x & 31, tc = threadIdx.x >> 5;   // 32 x 8
    #pragma unroll
    for (int r = 0; r < 4; r++) {
        int row = tc + r * 8;
        s[row][tr] = W1[(size_t)(k0 + row) * DIM + n0 + tr];
    }
    __syncthreads();
    #pragma unroll
    for (int r = 0; r < 4; r++) {
        int row = tc + r * 8;                                 // n-local
        float v = s[tr][row];
        w1hi[(size_t)(n0 + row) * DIM + k0 + tr] = split_hi(v);
        w1lo[(size_t)(n0 + row) * DIM + k0 + tr] = split_lo(v);
    }
}

__global__ __launch_bounds__(256) void convert_w2t(const float* __restrict__ W2,
                                                   uint32_t* __restrict__ W2Tp) {
    int i = blockIdx.x * 256 + threadIdx.x;   // over 64*2048
    int e = i >> 11, n = i & 2047;
    W2Tp[i] = pack_split(W2[(size_t)n * NEXP + e]);
}

// in-place packed converter (round-3 mid-fallback path)
__global__ __launch_bounds__(256) void convert_x_inplace(float* __restrict__ x) {
    size_t i = ((size_t)blockIdx.x * 256 + threadIdx.x) * 4;
    float4 v = *(const float4*)(x + i);
    uint4 p;
    p.x = pack_split(v.x); p.y = pack_split(v.y);
    p.z = pack_split(v.z); p.w = pack_split(v.w);
    *(uint4*)(x + i) = p;
}

__global__ __launch_bounds__(256) void convert_w1t_packed(
    const float* __restrict__ W1, uint32_t* __restrict__ W1Tp)
{
    __shared__ float s[32][33];
    const int k0 = blockIdx.y * 32, n0 = blockIdx.x * 32;
    const int tr = threadIdx.x & 31, tc = threadIdx.x >> 5;
    #pragma unroll
    for (int r = 0; r < 4; r++) {
        int row = tc + r * 8;
        s[row][tr] = W1[(size_t)(k0 + row) * DIM + n0 + tr];
    }
    __syncthreads();
    #pragma unroll
    for (int r = 0; r < 4; r++) {
        int row = tc + r * 8;
        W1Tp[(size_t)(n0 + row) * DIM + k0 + tr] = pack_split(s[tr][row]);
    }
}

// ---------------------------------------------------------------------------
// fused GEMM v2: split hi/lo staging (no unpack VALU in main loop)
// ---------------------------------------------------------------------------
__global__ __launch_bounds__(256, 2) void gemm_fused_v2(
    const _Float16* __restrict__ xhi, const _Float16* __restrict__ xlo,
    const _Float16* __restrict__ w1hi, const _Float16* __restrict__ w1lo,
    const float* __restrict__ b1, const uint32_t* __restrict__ W2Tp,
    float* __restrict__ Lp)
{
    __shared__ uint32_t smem[16384];          // 64 KB (main tiles / epilogue Hs)
    _Float16* As = (_Float16*)smem;           // [128][64] halves, 16 KB
    _Float16* Bs = (_Float16*)(smem + 4096);  // [128][64] halves, 16 KB

    const int t    = threadIdx.x;
    const int wid  = t >> 6;
    const int lane = t & 63;
    const int quad = lane >> 4;
    const int l16  = lane & 15;

    // block swizzle: groups of 8 m-blocks share one n-block (W1T slice L2 reuse)
    const int lin = blockIdx.x;               // 2048 blocks
    const int grp = lin >> 7;
    const int rem = lin & 127;
    const int m0 = (grp * 8 + (rem & 7)) * BM;
    const int n0 = (rem >> 3) * BN;

    // per-lane staging source pointers; LDS slot s of row r holds logical
    // chunk c = s ^ (r&7); c<4 -> hi array chunk c, else lo array chunk c-4.
    const _Float16* gA[4];
    const _Float16* gB[4];
    #pragma unroll
    for (int r = 0; r < 4; r++) {
        int s_lin = r * 256 + t;
        int row = s_lin >> 3;
        int c   = (s_lin & 7) ^ (row & 7);
        gA[r] = (c < 4) ? xhi  + (size_t)(m0 + row) * DIM + c * 8
                        : xlo  + (size_t)(m0 + row) * DIM + (c - 4) * 8;
        gB[r] = (c < 4) ? w1hi + (size_t)(n0 + row) * DIM + c * 8
                        : w1lo + (size_t)(n0 + row) * DIM + (c - 4) * 8;
    }

    f32x4 am[4][4], ac[4][4];
    #pragma unroll
    for (int i = 0; i < 4; i++)
        #pragma unroll
        for (int j = 0; j < 4; j++) { am[i][j] = (f32x4)0.0f; ac[i][j] = (f32x4)0.0f; }

    const int wm = (wid & 1) * 64;
    const int wn = (wid >> 1) * 64;

    for (int k0 = 0; k0 < DIM; k0 += BKE) {
        #pragma unroll
        for (int r = 0; r < 4; r++) {
            const int wslot = (r * 256 + wid * 64) << 2;  // u32 index, wave-uniform
            __builtin_amdgcn_global_load_lds((const GLOBAL_AS uint32_t*)gA[r],
                                             (LDS_AS uint32_t*)(smem + wslot), 16, 0, 0);
            __builtin_amdgcn_global_load_lds((const GLOBAL_AS uint32_t*)gB[r],
                                             (LDS_AS uint32_t*)(smem + 4096 + wslot), 16, 0, 0);
            gA[r] += BKE; gB[r] += BKE;
        }
        __syncthreads();   // drains vmcnt -> staged data visible

        half8 ah[4], al[4], bh[4], bl[4];
        #pragma unroll
        for (int mt = 0; mt < 4; mt++)
            load_frag2(As, wm + mt * 16 + l16, quad, ah[mt], al[mt]);
        #pragma unroll
        for (int nt = 0; nt < 4; nt++)
            load_frag2(Bs, wn + nt * 16 + l16, quad, bh[nt], bl[nt]);

        #pragma unroll
        for (int mt = 0; mt < 4; mt++)
            #pragma unroll
            for (int nt = 0; nt < 4; nt++) {
                am[mt][nt] = __builtin_amdgcn_mfma_f32_16x16x32_f16(ah[mt], bh[nt], am[mt][nt], 0, 0, 0);
                ac[mt][nt] = __builtin_amdgcn_mfma_f32_16x16x32_f16(ah[mt], bl[nt], ac[mt][nt], 0, 0, 0);
                ac[mt][nt] = __builtin_amdgcn_mfma_f32_16x16x32_f16(al[mt], bh[nt], ac[mt][nt], 0, 0, 0);
            }
        __syncthreads();   // before next stage overwrites LDS
    }

    // ---- epilogue: bias + exact GELU, pack h into swizzled LDS [128][128] ----
    uint32_t* Hs = smem;
    #pragma unroll
    for (int mt = 0; mt < 4; mt++)
        #pragma unroll
        for (int nt = 0; nt < 4; nt++) {
            const int coln = wn + nt * 16 + l16;
            const float b1v = b1[n0 + coln];
            #pragma unroll
            for (int r = 0; r < 4; r++) {
                float h = am[mt][nt][r] + ac[mt][nt][r] * INV_LO_SCALE + b1v;
                h = 0.5f * h * (1.0f + erff(h * 0.70710678118654752440f));
                const int rowm = wm + mt * 16 + quad * 4 + r;
                const int word = rowm * 128 + ((((coln >> 2) ^ (rowm & 7)) << 2) | (coln & 3));
                Hs[word] = pack_split(h);
            }
        }
    __syncthreads();

    // ---- GEMM2: logits[128 x 64] = h[128 x 128] @ W2T' (4 K=32 steps) ----
    f32x4 a2m[2][4], a2c[2][4];
    #pragma unroll
    for (int i = 0; i < 2; i++)
        #pragma unroll
        for (int j = 0; j < 4; j++) { a2m[i][j] = (f32x4)0.0f; a2c[i][j] = (f32x4)0.0f; }

    #pragma unroll
    for (int ks = 0; ks < 4; ks++) {
        half8 a2h[2], a2l[2];
        #pragma unroll
        for (int mt2 = 0; mt2 < 2; mt2++) {
            const int row = wid * 32 + mt2 * 16 + l16;
            const int sw  = row & 7;
            const int cb  = ks * 8 + quad * 2;           // k = ks*32 + quad*8 + j
            const uint4 q0 = *(const uint4*)(Hs + row * 128 + ((cb ^ sw) << 2));
            const uint4 q1 = *(const uint4*)(Hs + row * 128 + (((cb + 1) ^ sw) << 2));
            uint32_t u[8] = {q0.x, q0.y, q0.z, q0.w, q1.x, q1.y, q1.z, q1.w};
            U4H8 H, L;
            #pragma unroll
            for (int j = 0; j < 4; j++) {
                H.u[j] = (u[2 * j] & 0xffffu) | (u[2 * j + 1] << 16);
                L.u[j] = (u[2 * j] >> 16)     | (u[2 * j + 1] & 0xffff0000u);
            }
            a2h[mt2] = H.h; a2l[mt2] = L.h;
        }
        #pragma unroll
        for (int et = 0; et < 4; et++) {
            const int e = et * 16 + l16;
            const uint32_t* wp = W2Tp + (size_t)e * DIM + n0 + ks * 32 + quad * 8;
            const uint4 q0 = *(const uint4*)wp;
            const uint4 q1 = *(const uint4*)(wp + 4);
            uint32_t u[8] = {q0.x, q0.y, q0.z, q0.w, q1.x, q1.y, q1.z, q1.w};
            U4H8 H, L;
            #pragma unroll
            for (int j = 0; j < 4; j++) {
                H.u[j] = (u[2 * j] & 0xffffu) | (u[2 * j + 1] << 16);
                L.u[j] = (u[2 * j] >> 16)     | (u[2 * j + 1] & 0xffff0000u);
            }
            #pragma unroll
            for (int mt2 = 0; mt2 < 2; mt2++) {
                a2m[mt2][et] = __builtin_amdgcn_mfma_f32_16x16x32_f16(a2h[mt2], H.h, a2m[mt2][et], 0, 0, 0);
                a2c[mt2][et] = __builtin_amdgcn_mfma_f32_16x16x32_f16(a2h[mt2], L.h, a2c[mt2][et], 0, 0, 0);
                a2c[mt2][et] = __builtin_amdgcn_mfma_f32_16x16x32_f16(a2l[mt2], H.h, a2c[mt2][et], 0, 0, 0);
            }
        }
    }

    #pragma unroll
    for (int mt2 = 0; mt2 < 2; mt2++)
        #pragma unroll
        for (int et = 0; et < 4; et++)
            #pragma unroll
            for (int r = 0; r < 4; r++) {
                const float lg = a2m[mt2][et][r] + a2c[mt2][et][r] * INV_LO_SCALE;
                const int rowm = m0 + wid * 32 + mt2 * 16 + quad * 4 + r;
                const int e = et * 16 + l16;
                atomicAdd(&Lp[(size_t)rowm * NEXP + e], lg);
            }
}

// ---------------------------------------------------------------------------
// round-3 packed-u32 fused GEMM (mid fallback, needs only ~21 MB ws)
// ---------------------------------------------------------------------------
__global__ __launch_bounds__(256, 2) void gemm_fused(
    const uint32_t* __restrict__ xp, const uint32_t* __restrict__ W1Tp,
    const float* __restrict__ b1, const uint32_t* __restrict__ W2Tp,
    float* __restrict__ Lp)
{
    __shared__ uint32_t smem[16384];
    uint32_t* Ap = smem;
    uint32_t* Bp = smem + 4096;

    const int t    = threadIdx.x;
    const int wid  = t >> 6;
    const int lane = t & 63;
    const int quad = lane >> 4;
    const int l16  = lane & 15;

    const int lin = blockIdx.x;
    const int grp = lin >> 7;
    const int rem = lin & 127;
    const int m0 = (grp * 8 + (rem & 7)) * BM;
    const int n0 = (rem >> 3) * BN;

    const uint32_t* gA[4];
    const uint32_t* gB[4];
    #pragma unroll
    for (int r = 0; r < 4; r++) {
        int s = r * 256 + t;
        int row = s >> 3;
        int c   = s & 7;
        int co  = (c ^ (row & 7)) << 2;
        gA[r] = xp   + (size_t)(m0 + row) * DIM + co;
        gB[r] = W1Tp + (size_t)(n0 + row) * DIM + co;
    }

    f32x4 am[4][4], ac[4][4];
    #pragma unroll
    for (int i = 0; i < 4; i++)
        #pragma unroll
        for (int j = 0; j < 4; j++) { am[i][j] = (f32x4)0.0f; ac[i][j] = (f32x4)0.0f; }

    const int wm = (wid & 1) * 64;
    const int wn = (wid >> 1) * 64;

    for (int k0 = 0; k0 < DIM; k0 += BKE) {
        #pragma unroll
        for (int r = 0; r < 4; r++) {
            const int wslot = (r * 256 + wid * 64) << 2;
            __builtin_amdgcn_global_load_lds((const GLOBAL_AS uint32_t*)gA[r],
                                             (LDS_AS uint32_t*)(Ap + wslot), 16, 0, 0);
            __builtin_amdgcn_global_load_lds((const GLOBAL_AS uint32_t*)gB[r],
                                             (LDS_AS uint32_t*)(Bp + wslot), 16, 0, 0);
            gA[r] += BKE; gB[r] += BKE;
        }
        __syncthreads();

        half8 ah[4], al[4], bh[4], bl[4];
        #pragma unroll
        for (int mt = 0; mt < 4; mt++)
            load_frag(Ap, wm + mt * 16 + l16, quad, ah[mt], al[mt]);
        #pragma unroll
        for (int nt = 0; nt < 4; nt++)
            load_frag(Bp, wn + nt * 16 + l16, quad, bh[nt], bl[nt]);

        #pragma unroll
        for (int mt = 0; mt < 4; mt++)
            #pragma unroll
            for (int nt = 0; nt < 4; nt++) {
                am[mt][nt] = __builtin_amdgcn_mfma_f32_16x16x32_f16(ah[mt], bh[nt], am[mt][nt], 0, 0, 0);
                ac[mt][nt] = __builtin_amdgcn_mfma_f32_16x16x32_f16(ah[mt], bl[nt], ac[mt][nt], 0, 0, 0);
                ac[mt][nt] = __builtin_amdgcn_mfma_f32_16x16x32_f16(al[mt], bh[nt], ac[mt][nt], 0, 0, 0);
            }
        __syncthreads();
    }

    uint32_t* Hs = smem;
    #pragma unroll
    for (int mt = 0; mt < 4; mt++)
        #pragma unroll
        for (int nt = 0; nt < 4; nt++) {
            const int coln = wn + nt * 16 + l16;
            const float b1v = b1[n0 + coln];
            #pragma unroll
            for (int r = 0; r < 4; r++) {
                float h = am[mt][nt][r] + ac[mt][nt][r] * INV_LO_SCALE + b1v;
                h = 0.5f * h * (1.0f + erff(h * 0.70710678118654752440f));
                const int rowm = wm + mt * 16 + quad * 4 + r;
                const int word = rowm * 128 + ((((coln >> 2) ^ (rowm & 7)) << 2) | (coln & 3));
                Hs[word] = pack_split(h);
            }
        }
    __syncthreads();

    f32x4 a2m[2][4], a2c[2][4];
    #pragma unroll
    for (int i = 0; i < 2; i++)
        #pragma unroll
        for (int j = 0; j < 4; j++) { a2m[i][j] = (f32x4)0.0f; a2c[i][j] = (f32x4)0.0f; }

    #pragma unroll
    for (int ks = 0; ks < 4; ks++) {
        half8 a2h[2], a2l[2];
        #pragma unroll
        for (int mt2 = 0; mt2 < 2; mt2++) {
            const int row = wid * 32 + mt2 * 16 + l16;
            const int sw  = row & 7;
            const int cb  = ks * 8 + quad * 2;
            const uint4 q0 = *(const uint4*)(Hs + row * 128 + ((cb ^ sw) << 2));
            const uint4 q1 = *(const uint4*)(Hs + row * 128 + (((cb + 1) ^ sw) << 2));
            uint32_t u[8] = {q0.x, q0.y, q0.z, q0.w, q1.x, q1.y, q1.z, q1.w};
            U4H8 H, L;
            #pragma unroll
            for (int j = 0; j < 4; j++) {
                H.u[j] = (u[2 * j] & 0xffffu) | (u[2 * j + 1] << 16);
                L.u[j] = (u[2 * j] >> 16)     | (u[2 * j + 1] & 0xffff0000u);
            }
            a2h[mt2] = H.h; a2l[mt2] = L.h;
        }
        #pragma unroll
        for (int et = 0; et < 4; et++) {
            const int e = et * 16 + l16;
            const uint32_t* wp = W2Tp + (size_t)e * DIM + n0 + ks * 32 + quad * 8;
            const uint4 q0 = *(const uint4*)wp;
            const uint4 q1 = *(const uint4*)(wp + 4);
            uint32_t u[8] = {q0.x, q0.y, q0.z, q0.w, q1.x, q1.y, q1.z, q1.w};
            U4H8 H, L;
            #pragma unroll
            for (int j = 0; j < 4; j++) {
                H.u[j] = (u[2 * j] & 0xffffu) | (u[2 * j + 1] << 16);
                L.u[j] = (u[2 * j] >> 16)     | (u[2 * j + 1] & 0xffff0000u);
            }
            #pragma unroll
            for (int mt2 = 0; mt2 < 2; mt2++) {
                a2m[mt2][et] = __builtin_amdgcn_mfma_f32_16x16x32_f16(a2h[mt2], H.h, a2m[mt2][et], 0, 0, 0);
                a2c[mt2][et] = __builtin_amdgcn_mfma_f32_16x16x32_f16(a2h[mt2], L.h, a2c[mt2][et], 0, 0, 0);
                a2c[mt2][et] = __builtin_amdgcn_mfma_f32_16x16x32_f16(a2l[mt2], H.h, a2c[mt2][et], 0, 0, 0);
            }
        }
    }

    #pragma unroll
    for (int mt2 = 0; mt2 < 2; mt2++)
        #pragma unroll
        for (int et = 0; et < 4; et++)
            #pragma unroll
            for (int r = 0; r < 4; r++) {
                const float lg = a2m[mt2][et][r] + a2c[mt2][et][r] * INV_LO_SCALE;
                const int rowm = m0 + wid * 32 + mt2 * 16 + quad * 4 + r;
                const int e = et * 16 + l16;
                atomicAdd(&Lp[(size_t)rowm * NEXP + e], lg);
            }
}

// ---------------------------------------------------------------------------
// routing: 256 persistent blocks, register->LDS->global aggregation
// ---------------------------------------------------------------------------
__global__ __launch_bounds__(256) void router_topk_v2(
    const float* __restrict__ Lp, const float* __restrict__ b2,
    float* __restrict__ out_rw, float* __restrict__ out_idx,
    float* __restrict__ gP, float* __restrict__ gI)
{
    __shared__ float sP[NEXP];
    __shared__ float sI[NEXP];
    const int t = threadIdx.x;
    if (t < NEXP) { sP[t] = 0.f; sI[t] = 0.f; }
    __syncthreads();

    const int lane = t & 63;
    const int wv   = t >> 6;
    const float b2v = b2[lane];

    float accP = 0.f, accSel = 0.f;

    for (int i = 0; i < 16; i++) {
        const int tok = blockIdx.x * 64 + i * 4 + wv;
        float logit = Lp[(size_t)tok * NEXP + lane] + b2v;

        // full softmax over 64 experts (load-balance loss)
        float mx = logit;
        #pragma unroll
        for (int off = 32; off >= 1; off >>= 1) mx = fmaxf(mx, __shfl_xor(mx, off));
        float p = expf(logit - mx);
        float ps = p;
        #pragma unroll
        for (int off = 32; off >= 1; off >>= 1) ps += __shfl_xor(ps, off);
        accP += p / ps;

        // iterative top-8 argmax (min-index tiebreak)
        float cur = logit;
        float tv[TOPK]; int tix[TOPK];
        for (int k = 0; k < TOPK; k++) {
            float v = cur; int idx = lane;
            #pragma unroll
            for (int off = 32; off >= 1; off >>= 1) {
                float ov = __shfl_xor(v, off);
                int   oi = __shfl_xor(idx, off);
                if (ov > v || (ov == v && oi < idx)) { v = ov; idx = oi; }
            }
            tv[k] = v; tix[k] = idx;
            if (lane == idx) cur = -INFINITY;
        }

        float ev[TOPK], s = 0.f;
        #pragma unroll
        for (int k = 0; k < TOPK; k++) { ev[k] = expf(tv[k] - tv[0]); s += ev[k]; }
        float w = 0.f;
        #pragma unroll
        for (int k = 0; k < TOPK; k++)
            if (tix[k] == lane) { w = ev[k] / s; accSel += 1.f; }

        out_rw[(size_t)tok * NEXP + lane] = w;
        if (lane < TOPK) out_idx[(size_t)tok * TOPK + lane] = (float)tix[lane];
    }

    atomicAdd(&sP[lane], accP);
    atomicAdd(&sI[lane], accSel);
    __syncthreads();
    if (t < NEXP) { atomicAdd(&gP[t], sP[t]); atomicAdd(&gI[t], sI[t]); }
}

__global__ void loss_kernel(const float* __restrict__ gP,
                            const float* __restrict__ gI,
                            float* __restrict__ out_loss)
{
    const int lane = threadIdx.x;
    const float inv = 1.0f / (float)N_TOK;
    float v = (gI[lane] * inv) * (gP[lane] * inv);
    #pragma unroll
    for (int off = 32; off >= 1; off >>= 1) v += __shfl_xor(v, off);
    if (lane == 0) out_loss[0] = (float)NEXP * v;
}

extern "C" void kernel_launch(void* const* d_in, const int* in_sizes, int n_in,
                              void* d_out, int out_size, void* d_ws, size_t ws_size,
                              hipStream_t stream) {
    const float* x  = (const float*)d_in[0];
    const float* W1 = (const float*)d_in[1];
    const float* b1 = (const float*)d_in[2];
    const float* W2 = (const float*)d_in[3];
    const float* b2 = (const float*)d_in[4];

    float* out_rw   = (float*)d_out;
    float* out_idx  = out_rw + (size_t)N_TOK * NEXP;
    float* out_loss = out_idx + (size_t)N_TOK * TOPK;

    // ---- split-path ws layout (needs ~149 MiB) ----
    const size_t SZ_X   = (size_t)N_TOK * DIM * 2;      // 64 MiB per array
    const size_t SZ_W1  = (size_t)DIM * DIM * 2;        // 8 MiB per array
    const size_t OFF_XHI   = 0;
    const size_t OFF_XLO   = OFF_XHI + SZ_X;
    const size_t OFF_W1HI  = OFF_XLO + SZ_X;
    const size_t OFF_W1LO  = OFF_W1HI + SZ_W1;
    const size_t OFF_W2T   = OFF_W1LO + SZ_W1;
    const size_t OFF_LP    = OFF_W2T + (size_t)DIM * NEXP * 4;
    const size_t OFF_G     = OFF_LP + (size_t)N_TOK * NEXP * 4;
    const size_t needed_v2 = OFF_G + 2 * NEXP * 4;

    // ---- packed-path ws layout (round 3, ~21 MiB) ----
    const size_t P_W1T = 0;
    const size_t P_W2T = (size_t)16 << 20;
    const size_t P_LP  = (size_t)17 << 20;
    const size_t P_G   = P_LP + (size_t)N_TOK * NEXP * 4;
    const size_t needed_p = P_G + 2 * NEXP * 4;

    if (ws_size >= needed_v2) {
        _Float16* xhi  = (_Float16*)((char*)d_ws + OFF_XHI);
        _Float16* xlo  = (_Float16*)((char*)d_ws + OFF_XLO);
        _Float16* w1hi = (_Float16*)((char*)d_ws + OFF_W1HI);
        _Float16* w1lo = (_Float16*)((char*)d_ws + OFF_W1LO);
        uint32_t* W2Tp = (uint32_t*)((char*)d_ws + OFF_W2T);
        float* Lp = (float*)((char*)d_ws + OFF_LP);
        float* gP = (float*)((char*)d_ws + OFF_G);
        float* gI = gP + NEXP;

        (void)hipMemsetAsync((char*)d_ws + OFF_LP, 0,
                             (size_t)N_TOK * NEXP * 4 + 2 * NEXP * 4, stream);
        convert_x_split  <<<(N_TOK * DIM) / (256 * 4), 256, 0, stream>>>(x, xhi, xlo);
        convert_w1t_split<<<dim3(DIM / 32, DIM / 32), 256, 0, stream>>>(W1, w1hi, w1lo);
        convert_w2t      <<<(NEXP * DIM) / 256, 256, 0, stream>>>(W2, W2Tp);
        gemm_fused_v2<<<(N_TOK / BM) * (DIM / BN), 256, 0, stream>>>(
            xhi, xlo, w1hi, w1lo, b1, W2Tp, Lp);
        router_topk_v2<<<N_TOK / 64, 256, 0, stream>>>(Lp, b2, out_rw, out_idx, gP, gI);
        loss_kernel<<<1, 64, 0, stream>>>(gP, gI, out_loss);
    } else if (ws_size >= needed_p) {
        uint32_t* W1Tp = (uint32_t*)((char*)d_ws + P_W1T);
        uint32_t* W2Tp = (uint32_t*)((char*)d_ws + P_W2T);
        float* Lp = (float*)((char*)d_ws + P_LP);
        float* gP = (float*)((char*)d_ws + P_G);
        float* gI = gP + NEXP;

        (void)hipMemsetAsync((char*)d_ws + P_LP, 0,
                             (size_t)N_TOK * NEXP * 4 + 2 * NEXP * 4, stream);
        convert_x_inplace<<<(N_TOK * DIM) / (256 * 4), 256, 0, stream>>>((float*)d_in[0]);
        convert_w1t_packed<<<dim3(DIM / 32, DIM / 32), 256, 0, stream>>>(W1, W1Tp);
        convert_w2t<<<(NEXP * DIM) / 256, 256, 0, stream>>>(W2, W2Tp);
        gemm_fused<<<(N_TOK / BM) * (DIM / BN), 256, 0, stream>>>(
            (const uint32_t*)d_in[0], W1Tp, b1, W2Tp, Lp);
        router_topk_v2<<<N_TOK / 64, 256, 0, stream>>>(Lp, b2, out_rw, out_idx, gP, gI);
        loss_kernel<<<1, 64, 0, stream>>>(gP, gI, out_loss);
    }
}